// Round 14
// baseline (353.843 us; speedup 1.0000x reference)
//
#include <hip/hip_runtime.h>

typedef float v2f __attribute__((ext_vector_type(2)));

#define T_LEN 2048
#define BB    128
#define CC    128
#define EE    32
#define HH    64
#define PRED  336
#define CH    28          // steps per chunk
#define NCH   12          // 12*28 = 336

// workspace layout (floats)
#define WS_MAG 0          // TRANSPOSED [h_out(col)][h_in(row)][2]  8192
#define WS_MR  8192       // [h_in][c] = W_o@Wr (interleaved)      8192
#define WS_CAG 16384      // [h][2]   = {b_o@W_in, b_o@W_g}         128
#define WS_CR  16512      // [c]      = b_o@Wr                      128
#define WS_V   16640      // [b][e]   = encoder output             4096

__device__ __forceinline__ v2f mk2(float a, float b) { v2f t; t.x = a; t.y = b; return t; }

__device__ __forceinline__ float bcast(unsigned ub, int k) {
#if __has_builtin(__builtin_amdgcn_readlane)
    return __builtin_bit_cast(float, (unsigned)__builtin_amdgcn_readlane((int)ub, k));
#else
    return __builtin_bit_cast(float, (unsigned)__shfl((int)ub, k, 64));
#endif
}

// permlane32_swap cross-half combine (consumer only; verified round-2):
__device__ __forceinline__ float swap_sum1(float X, float Y) {
    unsigned x = __builtin_bit_cast(unsigned, X);
    unsigned y = __builtin_bit_cast(unsigned, Y);
#if __has_builtin(__builtin_amdgcn_permlane32_swap)
    auto r = __builtin_amdgcn_permlane32_swap(x, y, false, false);
    return __builtin_bit_cast(float, (unsigned)r[0]) +
           __builtin_bit_cast(float, (unsigned)r[1]);
#else
    asm("v_permlane32_swap_b32 %0, %1" : "+v"(x), "+v"(y));
    return __builtin_bit_cast(float, x) + __builtin_bit_cast(float, y);
#endif
}

__device__ __forceinline__ v2f swap_sum(v2f X, v2f Y) {
    v2f z;
    z.x = swap_sum1(X.x, Y.x);
    z.y = swap_sum1(X.y, Y.y);
    return z;
}

// --- consumer named-register matrix (round-7 form, no volatile pins) -------
#define ROWS(F) F(0) F(1) F(2) F(3) F(4) F(5) F(6) F(7) F(8) F(9) F(10) F(11) \
                F(12) F(13) F(14) F(15) F(16) F(17) F(18) F(19) F(20) F(21)   \
                F(22) F(23) F(24) F(25) F(26) F(27) F(28) F(29) F(30) F(31)
#define DECLM(r) v2f mA##r, mB##r;
#define INITM(r) mA##r = Mrow[(rbase + r) * HH + p];      \
                 mB##r = Mrow[(rbase + r) * HH + p + 32];
#define FMAQ(q, a, b, c, d)                               \
    X0 += q.x * mA##a;  Y0 += q.x * mB##a;                \
    X1 += q.y * mA##b;  Y1 += q.y * mB##b;                \
    X0 += q.z * mA##c;  Y0 += q.z * mB##c;                \
    X1 += q.w * mA##d;  Y1 += q.w * mB##d;
#define FMA_ALL                                           \
    FMAQ(q0,  0,  1,  2,  3)  FMAQ(q1,  4,  5,  6,  7)    \
    FMAQ(q2,  8,  9, 10, 11)  FMAQ(q3, 12, 13, 14, 15)    \
    FMAQ(q4, 16, 17, 18, 19)  FMAQ(q5, 20, 21, 22, 23)    \
    FMAQ(q6, 24, 25, 26, 27)  FMAQ(q7, 28, 29, 30, 31)

// producer readlane-broadcast group: 8 float4 (16 rows) into one acc chain
#define PGRP(g, ACC)                                                        \
    _Pragma("unroll")                                                       \
    for (int k2 = 0; k2 < 8; ++k2) {                                        \
        float4 mm = Mcol4[(g) * 8 + k2];                                    \
        float s0 = bcast(ub, (g) * 16 + 2 * k2);                            \
        float s1 = bcast(ub, (g) * 16 + 2 * k2 + 1);                        \
        ACC.x += s0 * mm.x;  ACC.y += s0 * mm.y;                            \
        ACC.x += s1 * mm.z;  ACC.y += s1 * mm.w;                            \
    }

// ---------------------------------------------------------------------------
// Prep kernel.  Only change vs harness-verified version: WS_MAG is stored
// TRANSPOSED ([col][row]) so each producer lane's column is contiguous.
// ---------------------------------------------------------------------------
__global__ __launch_bounds__(256) void prep_kernel(
    const float* __restrict__ x,
    const float* __restrict__ WeT, const float* __restrict__ beT,
    const float* __restrict__ WeW, const float* __restrict__ beW,
    const float* __restrict__ WeD, const float* __restrict__ beD,
    const float* __restrict__ WeR, const float* __restrict__ beR,
    const float* __restrict__ Wdin, const float* __restrict__ Wdg,
    const float* __restrict__ Wdo,  const float* __restrict__ bdo,
    const float* __restrict__ Wr,
    float* __restrict__ ws)
{
    const int tid = threadIdx.x;

    if (blockIdx.x < BB) {
        __shared__ __align__(16) float s_x [T_LEN + 6];
        __shared__ __align__(16) float s_tr[T_LEN];
        __shared__ __align__(16) float s_rs[T_LEN];
        __shared__ __align__(16) float s_part[4][8][32];

        const int b = blockIdx.x;
        const float* xb = x + (size_t)b * T_LEN * CC;

        for (int i = tid; i < T_LEN + 6; i += 256) {
            int t = i - 3;
            t = t < 0 ? 0 : (t > T_LEN - 1 ? T_LEN - 1 : t);
            s_x[i] = xb[(size_t)t * CC];
        }
        __syncthreads();

        for (int t = tid; t < T_LEN; t += 256) {
            float s = 0.f;
            #pragma unroll
            for (int j = 0; j < 7; ++j) s += s_x[t + j];
            float tm = s * (1.0f / 7.0f);
            s_tr[t] = tm;
            s_rs[t] = s_x[t + 3] - tm;
        }
        __syncthreads();

        {
            const int e = tid & 31, tg = tid >> 5;
            float a0 = 0.f, a1 = 0.f, a2 = 0.f, a3 = 0.f;
            #pragma unroll 4
            for (int j = 0; j < 256; ++j) {
                int lt = tg * 256 + j;
                int wi = lt * EE + e;
                float trv = s_tr[lt], rsv = s_rs[lt];
                a0 += trv * WeT[wi];
                a1 += rsv * WeW[wi];
                a2 += rsv * WeD[wi];
                a3 += rsv * WeR[wi];
            }
            s_part[0][tg][e] = a0;
            s_part[1][tg][e] = a1;
            s_part[2][tg][e] = a2;
            s_part[3][tg][e] = a3;
        }
        __syncthreads();

        if (tid < EE) {
            float s0 = 0.f, s1 = 0.f, s2 = 0.f, s3 = 0.f;
            #pragma unroll
            for (int g = 0; g < 8; ++g) {
                s0 += s_part[0][g][tid];
                s1 += s_part[1][g][tid];
                s2 += s_part[2][g][tid];
                s3 += s_part[3][g][tid];
            }
            ws[WS_V + b * EE + tid] =
                  tanhf(s0 + beT[tid]) + tanhf(s1 + beW[tid])
                + tanhf(s2 + beD[tid]) + tanhf(s3 + beR[tid]);
        }
        return;
    }

    // ---- M precompute: 16 blocks x 256 threads = 4096 threads
    const int t0 = (blockIdx.x - BB) * 256 + tid;       // 0..4095
    const int hp = t0 >> 6;                             // h_in (row) = 0..63
    const int j  = t0 & 63;                             // h_out (col), or chan-pair
    float mi = 0.f, mg = 0.f, r0 = 0.f, r1 = 0.f;
    #pragma unroll 4
    for (int e = 0; e < EE; ++e) {
        float wo = Wdo[hp * EE + e];
        mi += wo * Wdin[e * HH + j];
        mg += wo * Wdg [e * HH + j];
        r0 += wo * Wr  [e * CC + 2 * j];
        r1 += wo * Wr  [e * CC + 2 * j + 1];
    }
    // TRANSPOSED store: [col j][row hp]
    ws[WS_MAG + (j * HH + hp) * 2    ] = mi;
    ws[WS_MAG + (j * HH + hp) * 2 + 1] = mg;
    // M_r stays [row][chan] for the consumer's half-split scheme
    ws[WS_MR  + hp * CC + 2 * j      ] = r0;
    ws[WS_MR  + hp * CC + 2 * j + 1  ] = r1;

    if (t0 < HH) {
        float ci = 0.f, cg = 0.f;
        for (int e = 0; e < EE; ++e) {
            float bo = bdo[e];
            ci += bo * Wdin[e * HH + t0];
            cg += bo * Wdg [e * HH + t0];
        }
        ws[WS_CAG + t0 * 2    ] = ci;
        ws[WS_CAG + t0 * 2 + 1] = cg;
    } else if (t0 < HH + CC) {
        int c = t0 - HH;
        float cr = 0.f;
        for (int e = 0; e < EE; ++e) cr += bdo[e] * Wr[e * CC + c];
        ws[WS_CR + c] = cr;
    }
}

// ---------------------------------------------------------------------------
// Scan kernel: one block per batch element, TWO waves.
// Wave 0 (producer): per step u = silu(A)*sigm(G); ds_write u (fire & forget
//   for the consumer); broadcast u via v_readlane (NO LDS readback on the
//   recurrence — rounds 7-11 showed the LDS write->read roundtrip, not
//   matrix reloads, dominates the serial chain); lane l owns FULL column l
//   of transposed M_ag (contiguous 32 x float4), 64 pk-FMAs in 4 chains.
// Wave 1 (consumer): incremental P += c_r + u_n @ M_r via LDS ring reads +
//   half-split + permlane swap (has chunk-level slack; unchanged).
// ---------------------------------------------------------------------------
__global__ __launch_bounds__(128, 1) void scan_kernel(
    const float* __restrict__ ws,
    const float* __restrict__ Wdin, const float* __restrict__ bdin,
    const float* __restrict__ Wdg,  const float* __restrict__ bdg,
    const float* __restrict__ Wr,   const float* __restrict__ br,
    float* __restrict__ out)
{
    __shared__ __align__(16) float s_v[EE];
    __shared__ __align__(16) float s_u[2][CH][HH];     // 14336 B ring

    const int tid  = threadIdx.x;
    const int wid  = tid >> 6;
    const int lane = tid & 63;
    const int half = lane >> 5;       // consumer: which 32-row half
    const int p    = lane & 31;       // consumer: column (group-local) index
    const int b    = blockIdx.x;

    if (tid < EE) s_v[tid] = ws[WS_V + b * EE + tid];
    __syncthreads();

    if (wid == 0) {
        // ================= producer =================
        // own column of transposed M_ag: 64 v2f contiguous = 32 float4
        const float4* Mcol4 = (const float4*)(ws + WS_MAG) + lane * (HH / 2);
        const v2f c_ag = ((const v2f*)(ws + WS_CAG))[lane];

        v2f ag = mk2(bdin[lane], bdg[lane]);
        {
            v2f t0 = mk2(0.f, 0.f), t1 = mk2(0.f, 0.f);
            for (int e = 0; e < EE; e += 2) {
                float v0 = s_v[e], v1 = s_v[e + 1];
                t0.x += v0 * Wdin[e * HH + lane];
                t0.y += v0 * Wdg [e * HH + lane];
                t1.x += v1 * Wdin[(e + 1) * HH + lane];
                t1.y += v1 * Wdg [(e + 1) * HH + lane];
            }
            ag += t0 + t1;
        }

        for (int c = 0; c < NCH + 1; ++c) {
            if (c < NCH) {
                float* ring = &s_u[c & 1][0][0];
                for (int i = 0; i < CH; ++i) {
                    float a = ag.x, g = ag.y;
                    float ea = __expf(-a), eg = __expf(-g);
                    float u = a * __builtin_amdgcn_rcpf((1.f + ea) * (1.f + eg));
                    ring[i * HH + lane] = u;            // consumer's copy

                    const unsigned ub = __builtin_bit_cast(unsigned, u);
                    v2f A0 = c_ag;
                    v2f A1 = mk2(0.f, 0.f);
                    v2f A2 = mk2(0.f, 0.f);
                    v2f A3 = mk2(0.f, 0.f);
                    PGRP(0, A0)
                    PGRP(1, A1)
                    PGRP(2, A2)
                    PGRP(3, A3)
                    ag += (A0 + A1) + (A2 + A3);
                }
            }
            __syncthreads();
        }
    } else {
        // ================= consumer =================
        const v2f* Mrow = (const v2f*)(ws + WS_MR);    // row stride CC/2==HH v2f
        const int rbase = half << 5;
        ROWS(DECLM)
        ROWS(INITM)
        const v2f c_r2 = ((const v2f*)(ws + WS_CR))[lane];

        // P starts at Q0 = v0 @ Wr + br (own channel pair); then incremental:
        // P_n = P_{n-1} + c_r + u_n @ M_r
        v2f P = ((const v2f*)br)[lane];
        {
            v2f t0 = mk2(0.f, 0.f), t1 = mk2(0.f, 0.f);
            for (int e = 0; e < EE; e += 2) {
                t0 += s_v[e]     * ((const v2f*)(Wr + e * CC))[lane];
                t1 += s_v[e + 1] * ((const v2f*)(Wr + (e + 1) * CC))[lane];
            }
            P += t0 + t1;
        }

        v2f* outb = (v2f*)(out + (size_t)b * PRED * CC);

        for (int c = 0; c < NCH + 1; ++c) {
            if (c > 0) {
                const float* ring = &s_u[(c - 1) & 1][0][0];
                const int n0 = (c - 1) * CH;
                for (int i = 0; i < CH; ++i) {
                    const float4* u4 = (const float4*)(ring + i * HH + (half << 5));
                    float4 q0 = u4[0], q1 = u4[1], q2 = u4[2], q3 = u4[3];
                    float4 q4 = u4[4], q5 = u4[5], q6 = u4[6], q7 = u4[7];
                    v2f X0 = mk2(0.f, 0.f), X1 = mk2(0.f, 0.f);
                    v2f Y0 = mk2(0.f, 0.f), Y1 = mk2(0.f, 0.f);
                    FMA_ALL
                    P += swap_sum(X0 + X1, Y0 + Y1) + c_r2;
                    outb[(size_t)(n0 + i) * (CC / 2) + lane] = P;
                }
            }
            __syncthreads();
        }
    }
}

extern "C" void kernel_launch(void* const* d_in, const int* in_sizes, int n_in,
                              void* d_out, int out_size, void* d_ws, size_t ws_size,
                              hipStream_t stream)
{
    const float* x    = (const float*)d_in[0];
    const float* WeT  = (const float*)d_in[1];
    const float* beT  = (const float*)d_in[2];
    const float* WeW  = (const float*)d_in[3];
    const float* beW  = (const float*)d_in[4];
    const float* WeD  = (const float*)d_in[5];
    const float* beD  = (const float*)d_in[6];
    const float* WeR  = (const float*)d_in[7];
    const float* beR  = (const float*)d_in[8];
    const float* Wdin = (const float*)d_in[9];
    const float* bdin = (const float*)d_in[10];
    const float* Wdg  = (const float*)d_in[11];
    const float* bdg  = (const float*)d_in[12];
    const float* Wdo  = (const float*)d_in[13];
    const float* bdo  = (const float*)d_in[14];
    const float* Wr   = (const float*)d_in[15];
    const float* br   = (const float*)d_in[16];

    float* ws  = (float*)d_ws;
    float* out = (float*)d_out;

    prep_kernel<<<BB + 16, 256, 0, stream>>>(x, WeT, beT, WeW, beW, WeD, beD,
                                             WeR, beR, Wdin, Wdg, Wdo, bdo,
                                             Wr, ws);
    scan_kernel<<<BB, 128, 0, stream>>>(ws, Wdin, bdin, Wdg, bdg, Wr, br, out);
}

// Round 17
// 331.648 us; speedup vs baseline: 1.0669x; 1.0669x over previous
//
#include <hip/hip_runtime.h>

typedef float v2f __attribute__((ext_vector_type(2)));

#define T_LEN 2048
#define BB    128
#define CC    128
#define EE    32
#define HH    64
#define PRED  336
#define CH    28          // steps per chunk
#define NCH   12          // 12*28 = 336

// workspace layout (floats)
#define WS_MAG 0          // PACKED [lane][row_local][colgroup] v2f   8192
#define WS_MR  8192       // PACKED [lane][row_local][colgroup] v2f   8192
#define WS_CAG 16384      // [h][2]   = {b_o@W_in, b_o@W_g}            128
#define WS_CR  16512      // [c]      = b_o@Wr                         128
#define WS_V   16640      // [b][e]   = encoder output                4096

__device__ __forceinline__ v2f mk2(float a, float b) { v2f t; t.x = a; t.y = b; return t; }

// permlane32_swap cross-half combine (harness-verified round-2):
__device__ __forceinline__ float swap_sum1(float X, float Y) {
    unsigned x = __builtin_bit_cast(unsigned, X);
    unsigned y = __builtin_bit_cast(unsigned, Y);
#if __has_builtin(__builtin_amdgcn_permlane32_swap)
    auto r = __builtin_amdgcn_permlane32_swap(x, y, false, false);
    return __builtin_bit_cast(float, (unsigned)r[0]) +
           __builtin_bit_cast(float, (unsigned)r[1]);
#else
    asm("v_permlane32_swap_b32 %0, %1" : "+v"(x), "+v"(y));
    return __builtin_bit_cast(float, x) + __builtin_bit_cast(float, y);
#endif
}

__device__ __forceinline__ v2f swap_sum(v2f X, v2f Y) {
    v2f z;
    z.x = swap_sum1(X.x, Y.x);
    z.y = swap_sum1(X.y, Y.y);
    return z;
}

// --- per-lane matrix: 32 rows x {A,B} col-groups -----------------------------
// r14 lesson: readlane broadcast REGRESSED (64 dependent readlanes on the
// serial chain).  Reverted to the r9 LDS-roundtrip structure (best measured).
// New this round: the matrix is stored PACKED per lane (contiguous 512 B), so
// the compiler's unavoidable per-step remat-reloads fold to 32 x dwordx4
// instead of 64 x dwordx2 — halving the VMEM issue slots on the issue-bound
// producer wave.  (Register pinning was tried 3x: VGPR stuck at 84-88.)
#define ROWS(F) F(0) F(1) F(2) F(3) F(4) F(5) F(6) F(7) F(8) F(9) F(10) F(11) \
                F(12) F(13) F(14) F(15) F(16) F(17) F(18) F(19) F(20) F(21)   \
                F(22) F(23) F(24) F(25) F(26) F(27) F(28) F(29) F(30) F(31)
#define DECLM(r) v2f mA##r, mB##r;
#define INITM(r) { float4 f = Mlane4[r];                  \
                   mA##r = mk2(f.x, f.y);                 \
                   mB##r = mk2(f.z, f.w); }
#define KEEPM(r) asm("" : "+v"(mA##r)); asm("" : "+v"(mB##r));
#define FMAQ(q, a, b, c, d)                               \
    X0 += q.x * mA##a;  Y0 += q.x * mB##a;                \
    X1 += q.y * mA##b;  Y1 += q.y * mB##b;                \
    X0 += q.z * mA##c;  Y0 += q.z * mB##c;                \
    X1 += q.w * mA##d;  Y1 += q.w * mB##d;
#define FMA_ALL                                           \
    FMAQ(q0,  0,  1,  2,  3)  FMAQ(q1,  4,  5,  6,  7)    \
    FMAQ(q2,  8,  9, 10, 11)  FMAQ(q3, 12, 13, 14, 15)    \
    FMAQ(q4, 16, 17, 18, 19)  FMAQ(q5, 20, 21, 22, 23)    \
    FMAQ(q6, 24, 25, 26, 27)  FMAQ(q7, 28, 29, 30, 31)

// ---------------------------------------------------------------------------
// Prep kernel.  Only change vs harness-verified version: M_ag and M_r are
// written in the per-lane PACKED layout:
//   float index = L*128 + rl*4 + cg*2, L = (row>>5)*32 + (col&31),
//   rl = row&31, cg = col>>5  — so lane L's 64 v2f are contiguous (32 float4).
// ---------------------------------------------------------------------------
__global__ __launch_bounds__(256) void prep_kernel(
    const float* __restrict__ x,
    const float* __restrict__ WeT, const float* __restrict__ beT,
    const float* __restrict__ WeW, const float* __restrict__ beW,
    const float* __restrict__ WeD, const float* __restrict__ beD,
    const float* __restrict__ WeR, const float* __restrict__ beR,
    const float* __restrict__ Wdin, const float* __restrict__ Wdg,
    const float* __restrict__ Wdo,  const float* __restrict__ bdo,
    const float* __restrict__ Wr,
    float* __restrict__ ws)
{
    const int tid = threadIdx.x;

    if (blockIdx.x < BB) {
        __shared__ __align__(16) float s_x [T_LEN + 6];
        __shared__ __align__(16) float s_tr[T_LEN];
        __shared__ __align__(16) float s_rs[T_LEN];
        __shared__ __align__(16) float s_part[4][8][32];

        const int b = blockIdx.x;
        const float* xb = x + (size_t)b * T_LEN * CC;

        for (int i = tid; i < T_LEN + 6; i += 256) {
            int t = i - 3;
            t = t < 0 ? 0 : (t > T_LEN - 1 ? T_LEN - 1 : t);
            s_x[i] = xb[(size_t)t * CC];
        }
        __syncthreads();

        for (int t = tid; t < T_LEN; t += 256) {
            float s = 0.f;
            #pragma unroll
            for (int j = 0; j < 7; ++j) s += s_x[t + j];
            float tm = s * (1.0f / 7.0f);
            s_tr[t] = tm;
            s_rs[t] = s_x[t + 3] - tm;
        }
        __syncthreads();

        {
            const int e = tid & 31, tg = tid >> 5;
            float a0 = 0.f, a1 = 0.f, a2 = 0.f, a3 = 0.f;
            #pragma unroll 4
            for (int j = 0; j < 256; ++j) {
                int lt = tg * 256 + j;
                int wi = lt * EE + e;
                float trv = s_tr[lt], rsv = s_rs[lt];
                a0 += trv * WeT[wi];
                a1 += rsv * WeW[wi];
                a2 += rsv * WeD[wi];
                a3 += rsv * WeR[wi];
            }
            s_part[0][tg][e] = a0;
            s_part[1][tg][e] = a1;
            s_part[2][tg][e] = a2;
            s_part[3][tg][e] = a3;
        }
        __syncthreads();

        if (tid < EE) {
            float s0 = 0.f, s1 = 0.f, s2 = 0.f, s3 = 0.f;
            #pragma unroll
            for (int g = 0; g < 8; ++g) {
                s0 += s_part[0][g][tid];
                s1 += s_part[1][g][tid];
                s2 += s_part[2][g][tid];
                s3 += s_part[3][g][tid];
            }
            ws[WS_V + b * EE + tid] =
                  tanhf(s0 + beT[tid]) + tanhf(s1 + beW[tid])
                + tanhf(s2 + beD[tid]) + tanhf(s3 + beR[tid]);
        }
        return;
    }

    // ---- M precompute: 16 blocks x 256 threads = 4096 threads
    const int t0 = (blockIdx.x - BB) * 256 + tid;       // 0..4095
    const int hp = t0 >> 6;                             // row = 0..63
    const int j  = t0 & 63;                             // col (h_out or chan-pair)
    float mi = 0.f, mg = 0.f, r0 = 0.f, r1 = 0.f;
    #pragma unroll 4
    for (int e = 0; e < EE; ++e) {
        float wo = Wdo[hp * EE + e];
        mi += wo * Wdin[e * HH + j];
        mg += wo * Wdg [e * HH + j];
        r0 += wo * Wr  [e * CC + 2 * j];
        r1 += wo * Wr  [e * CC + 2 * j + 1];
    }
    // PACKED per-lane store
    const int L   = ((hp >> 5) << 5) | (j & 31);        // destination lane
    const int rl  = hp & 31;                            // local row
    const int cg  = j >> 5;                             // col-group (A/B)
    const int off = L * 128 + rl * 4 + cg * 2;
    ws[WS_MAG + off    ] = mi;
    ws[WS_MAG + off + 1] = mg;
    ws[WS_MR  + off    ] = r0;
    ws[WS_MR  + off + 1] = r1;

    if (t0 < HH) {
        float ci = 0.f, cg2 = 0.f;
        for (int e = 0; e < EE; ++e) {
            float bo = bdo[e];
            ci  += bo * Wdin[e * HH + t0];
            cg2 += bo * Wdg [e * HH + t0];
        }
        ws[WS_CAG + t0 * 2    ] = ci;
        ws[WS_CAG + t0 * 2 + 1] = cg2;
    } else if (t0 < HH + CC) {
        int c = t0 - HH;
        float cr = 0.f;
        for (int e = 0; e < EE; ++e) cr += bdo[e] * Wr[e * CC + c];
        ws[WS_CR + c] = cr;
    }
}

// ---------------------------------------------------------------------------
// Scan kernel: one block per batch element, TWO waves (r9 structure, best
// measured at scan=100.3 us).
// Wave 0 (producer): per step u = silu(A)*sigm(G); ds_write u; read own
//   32-row half (8 x ds_read_b128); 64 packed FMAs in 4 chains; permlane
//   swap recombine.  Matrix reloads now fold to 32 x dwordx4 (packed layout).
// Wave 1 (consumer): incremental P += c_r + u_n @ M_r, same scheme.
// ---------------------------------------------------------------------------
__global__ __launch_bounds__(128, 1) void scan_kernel(
    const float* __restrict__ ws,
    const float* __restrict__ Wdin, const float* __restrict__ bdin,
    const float* __restrict__ Wdg,  const float* __restrict__ bdg,
    const float* __restrict__ Wr,   const float* __restrict__ br,
    float* __restrict__ out)
{
    __shared__ __align__(16) float s_v[EE];
    __shared__ __align__(16) float s_u[2][CH][HH];     // 14336 B ring

    const int tid  = threadIdx.x;
    const int wid  = tid >> 6;
    const int lane = tid & 63;
    const int half = lane >> 5;       // which 32-row half this lane reduces
    const int b    = blockIdx.x;

    if (tid < EE) s_v[tid] = ws[WS_V + b * EE + tid];
    __syncthreads();

    if (wid == 0) {
        // ================= producer =================
        const float4* Mlane4 = (const float4*)(ws + WS_MAG) + lane * 32;
        ROWS(DECLM)
        ROWS(INITM)
        ROWS(KEEPM)
        const v2f c_ag = ((const v2f*)(ws + WS_CAG))[lane];

        v2f ag = mk2(bdin[lane], bdg[lane]);
        {
            v2f t0 = mk2(0.f, 0.f), t1 = mk2(0.f, 0.f);
            for (int e = 0; e < EE; e += 2) {
                float v0 = s_v[e], v1 = s_v[e + 1];
                t0.x += v0 * Wdin[e * HH + lane];
                t0.y += v0 * Wdg [e * HH + lane];
                t1.x += v1 * Wdin[(e + 1) * HH + lane];
                t1.y += v1 * Wdg [(e + 1) * HH + lane];
            }
            ag += t0 + t1;
        }

        for (int c = 0; c < NCH + 1; ++c) {
            if (c < NCH) {
                float* ring = &s_u[c & 1][0][0];
                for (int i = 0; i < CH; ++i) {
                    float a = ag.x, g = ag.y;
                    float ea = __expf(-a), eg = __expf(-g);
                    float u = a * __builtin_amdgcn_rcpf((1.f + ea) * (1.f + eg));
                    ring[i * HH + lane] = u;

                    const float4* u4 = (const float4*)(ring + i * HH + (half << 5));
                    float4 q0 = u4[0], q1 = u4[1], q2 = u4[2], q3 = u4[3];
                    float4 q4 = u4[4], q5 = u4[5], q6 = u4[6], q7 = u4[7];
                    v2f X0 = mk2(0.f, 0.f), X1 = mk2(0.f, 0.f);
                    v2f Y0 = mk2(0.f, 0.f), Y1 = mk2(0.f, 0.f);
                    FMA_ALL
                    ag += swap_sum(X0 + X1, Y0 + Y1) + c_ag;
                }
            }
            __syncthreads();
        }
    } else {
        // ================= consumer =================
        const float4* Mlane4 = (const float4*)(ws + WS_MR) + lane * 32;
        ROWS(DECLM)
        ROWS(INITM)
        ROWS(KEEPM)
        const v2f c_r2 = ((const v2f*)(ws + WS_CR))[lane];

        // P starts at Q0 = v0 @ Wr + br (own channel pair); then incremental:
        // P_n = P_{n-1} + c_r + u_n @ M_r
        v2f P = ((const v2f*)br)[lane];
        {
            v2f t0 = mk2(0.f, 0.f), t1 = mk2(0.f, 0.f);
            for (int e = 0; e < EE; e += 2) {
                t0 += s_v[e]     * ((const v2f*)(Wr + e * CC))[lane];
                t1 += s_v[e + 1] * ((const v2f*)(Wr + (e + 1) * CC))[lane];
            }
            P += t0 + t1;
        }

        v2f* outb = (v2f*)(out + (size_t)b * PRED * CC);

        for (int c = 0; c < NCH + 1; ++c) {
            if (c > 0) {
                const float* ring = &s_u[(c - 1) & 1][0][0];
                const int n0 = (c - 1) * CH;
                for (int i = 0; i < CH; ++i) {
                    const float4* u4 = (const float4*)(ring + i * HH + (half << 5));
                    float4 q0 = u4[0], q1 = u4[1], q2 = u4[2], q3 = u4[3];
                    float4 q4 = u4[4], q5 = u4[5], q6 = u4[6], q7 = u4[7];
                    v2f X0 = mk2(0.f, 0.f), X1 = mk2(0.f, 0.f);
                    v2f Y0 = mk2(0.f, 0.f), Y1 = mk2(0.f, 0.f);
                    FMA_ALL
                    P += swap_sum(X0 + X1, Y0 + Y1) + c_r2;
                    outb[(size_t)(n0 + i) * (CC / 2) + lane] = P;
                }
            }
            __syncthreads();
        }
    }
}

extern "C" void kernel_launch(void* const* d_in, const int* in_sizes, int n_in,
                              void* d_out, int out_size, void* d_ws, size_t ws_size,
                              hipStream_t stream)
{
    const float* x    = (const float*)d_in[0];
    const float* WeT  = (const float*)d_in[1];
    const float* beT  = (const float*)d_in[2];
    const float* WeW  = (const float*)d_in[3];
    const float* beW  = (const float*)d_in[4];
    const float* WeD  = (const float*)d_in[5];
    const float* beD  = (const float*)d_in[6];
    const float* WeR  = (const float*)d_in[7];
    const float* beR  = (const float*)d_in[8];
    const float* Wdin = (const float*)d_in[9];
    const float* bdin = (const float*)d_in[10];
    const float* Wdg  = (const float*)d_in[11];
    const float* bdg  = (const float*)d_in[12];
    const float* Wdo  = (const float*)d_in[13];
    const float* bdo  = (const float*)d_in[14];
    const float* Wr   = (const float*)d_in[15];
    const float* br   = (const float*)d_in[16];

    float* ws  = (float*)d_ws;
    float* out = (float*)d_out;

    prep_kernel<<<BB + 16, 256, 0, stream>>>(x, WeT, beT, WeW, beW, WeD, beD,
                                             WeR, beR, Wdin, Wdg, Wdo, bdo,
                                             Wr, ws);
    scan_kernel<<<BB, 128, 0, stream>>>(ws, Wdin, bdin, Wdg, bdg, Wr, br, out);
}